// Round 1
// 575.746 us; speedup vs baseline: 1.0580x; 1.0580x over previous
//
#include <hip/hip_runtime.h>
#include <hip/hip_fp16.h>

// ---------- types ----------
typedef __bf16   bf16x8 __attribute__((ext_vector_type(8)));
typedef _Float16 f16x8  __attribute__((ext_vector_type(8)));
typedef float    f32x4  __attribute__((ext_vector_type(4)));
typedef unsigned short ushort8 __attribute__((ext_vector_type(8)));

// float -> bf16 RNE (finite inputs)
__device__ __forceinline__ unsigned short f2bf(float f){
  unsigned u = __builtin_bit_cast(unsigned, f);
  u = (u + 0x7FFFu + ((u >> 16) & 1u)) >> 16;
  return (unsigned short)u;
}

// tanh-form GELU with HW exp + HW rcp (v_rcp_f32, ~1 ulp — negligible vs f16
// rounding already accepted in h1/h2). Overflow-safe: e=inf -> rcp=0 -> t=1.
__device__ __forceinline__ float gelu_fast(float x){
  float u = 0.7978845608f * x * __builtin_fmaf(0.044715f, x * x, 1.0f);
  float e = __expf(2.0f * __builtin_fabsf(u));
  float t = __builtin_fmaf(-2.0f, __builtin_amdgcn_rcpf(e + 1.0f), 1.0f); // tanh(|u|)
  t = __builtin_copysignf(t, u);
  return 0.5f * x * (1.0f + t);
}

// stable softplus with HW exp/log
__device__ __forceinline__ float softplus_fast(float x){
  float e = __expf(-__builtin_fabsf(x));
  return fmaxf(x, 0.0f) + __logf(1.0f + e);
}

// ---------- kernel 0: pack mix_w into MFMA B-fragment order (bf16) ----------
// Wt[K=j*16+d][N=i*16+k] = mix_w[i][j][k][d];  frag f = ntile*4 + kstep,
// lane L holds B[k = kstep*32 + (L>>4)*8 + j][n = ntile*16 + (L&15)], j=0..7.
__global__ void prepack_wt(const float* __restrict__ mix_w,
                           unsigned short* __restrict__ wt){
  int tid = blockIdx.x * 256 + threadIdx.x;      // 0..2047
  int f = tid >> 6, L = tid & 63;
  int ks = f & 3, nt = f >> 2;
  int q = L >> 4, c = L & 15;
  int N = nt * 16 + c;
  int i = N >> 4, ko = N & 15;
  unsigned pk[4];
#pragma unroll
  for (int p = 0; p < 4; ++p){
    int K0 = ks * 32 + q * 8 + 2 * p;
    int K1 = K0 + 1;
    unsigned lo = f2bf(mix_w[((i*8 + (K0>>4))*16 + ko)*16 + (K0&15)]);
    unsigned hi = f2bf(mix_w[((i*8 + (K1>>4))*16 + ko)*16 + (K1&15)]);
    pk[p] = lo | (hi << 16);
  }
  uint4 v; v.x = pk[0]; v.y = pk[1]; v.z = pk[2]; v.w = pk[3];
  ((uint4*)wt)[tid] = v;
}

// ---------- main fused kernel: 64 rows/block, 256 threads (4 waves) ----------
// LDS: h1s 8192 + h2s 8192 + gatesS 32 = 16448 B (was 52736 -> 3 blocks/CU).
// Occupancy now VGPR-capped (~6 blocks/CU target). z is NOT staged in LDS:
// the norm pass makes the 32 KB tile L2-resident; mixing A-fragments and the
// epilogue re-read it from global (L2/L3 hit).
// h1s/h2s layout: [64 rows][64 cols] f16 with 16B-unit XOR swizzle
//   addr(row,col) = row*64 + (((col>>3) ^ (row&7))*8) + (col&7)
// so A-fragment ds_read_b128 (16 lanes = 16 rows, same k-range) spreads over
// all banks (2-way max = free) with zero padding.
__global__ __launch_bounds__(256, 5)
void soft_eq_kernel(const float* __restrict__ z,
                    const float* __restrict__ w1,  const float* __restrict__ b1,
                    const float* __restrict__ w2,  const float* __restrict__ b2,
                    const float* __restrict__ w3,  const float* __restrict__ gate_bias,
                    const unsigned short* __restrict__ wt,
                    float* __restrict__ out){
  __shared__ __align__(16) _Float16 h1s[64 * 64];
  __shared__ __align__(16) _Float16 h2s[64 * 64];
  __shared__ float gatesS[8];
  // overlays (disjoint lifetimes, separated by barriers):
  //   normsS lives in h2s region: written phase A, read phase B; h2s written C.
  //   scalesS lives in h1s region: h1s last read in C; scalesS written D, read F.
  float (*normsS)[8] = (float(*)[8])h2s;
  float (*scalesS)[9] = (float(*)[9])h1s;   // stride 9: kills 4-way bank conflict
                                            // on q-strided broadcast reads (2304 B fits)

  const int t = threadIdx.x;
  const size_t base = (size_t)blockIdx.x * (64 * 128);
  const float4* zg = (const float4*)(z + base);

  // ---- phase A: per-bundle norms (z read is the compulsory HBM pass) ----
#pragma unroll
  for (int it = 0; it < 8; ++it){
    int idx = t + it * 256;             // float4 index in [0,2048)
    float4 v = zg[idx];
    int r  = idx >> 5;                  // row in tile
    int bi = (idx & 31) >> 2;           // bundle index 0..7
    float ss = v.x*v.x + v.y*v.y + v.z*v.z + v.w*v.w;
    ss += __shfl_xor(ss, 1);
    ss += __shfl_xor(ss, 2);
    if ((t & 3) == 0) normsS[r][bi] = sqrtf(ss) + 1e-8f;
  }

  // register-cache per-neuron w1 row + b1 (L1-resident)
  const int i = t & 63, rg = t >> 6;
  float w1r[8];
  { const float4* p = (const float4*)(w1 + i * 8);
    float4 a = p[0], bq = p[1];
    w1r[0]=a.x; w1r[1]=a.y; w1r[2]=a.z; w1r[3]=a.w;
    w1r[4]=bq.x; w1r[5]=bq.y; w1r[6]=bq.z; w1r[7]=bq.w; }
  const float b1r = b1[i];
  __syncthreads();

  // ---- phase B: MLP1  h1 = gelu(norms @ w1^T + b1), f32 VALU (K=8) ----
#pragma unroll
  for (int chunk = 0; chunk < 16; ++chunk){
    int r = chunk * 4 + rg;
    const float4* np = (const float4*)normsS[r];       // wave-broadcast reads
    float4 n0 = np[0], n1 = np[1];
    float pre = b1r + n0.x*w1r[0] + n0.y*w1r[1] + n0.z*w1r[2] + n0.w*w1r[3]
                    + n1.x*w1r[4] + n1.y*w1r[5] + n1.z*w1r[6] + n1.w*w1r[7];
    int u = (i >> 3) ^ (r & 7);                        // swizzled 16B unit
    h1s[r * 64 + u * 8 + (i & 7)] = (_Float16)gelu_fast(pre);
  }
  __syncthreads();

  const int w = rg, L = t & 63, q = L >> 4, c = L & 15;
  const int am = w * 16 + c;            // A row for this lane (m = lane&15)

  // ---- phase C: MLP2 via f16 MFMA  h2 = gelu(h1 @ w2^T + b2) ----
  // M=N=K=64: wave w owns m-slab w*16; 4 n-tiles x 2 k-steps = 8 MFMA/wave.
  // Same numerics as old dot2 path (f16 in, f32 accumulate).
  f16x8 a2[2];
#pragma unroll
  for (int ks = 0; ks < 2; ++ks){
    int u = (ks * 4 + q) ^ (am & 7);
    a2[ks] = *(const f16x8*)&h1s[am * 64 + u * 8];     // conflict-free b128
  }
#pragma unroll
  for (int nt = 0; nt < 4; ++nt){
    int n = nt * 16 + c;
    f32x4 acc2 = {};
#pragma unroll
    for (int ks = 0; ks < 2; ++ks){
      // B[k][n] = w2[n][k]: k-contiguous 8 floats = exact B-fragment order
      const float4* wp = (const float4*)(w2 + n * 64 + ks * 32 + q * 8);
      float4 v0 = wp[0], v1 = wp[1];
      f16x8 bf;
      bf[0]=(_Float16)v0.x; bf[1]=(_Float16)v0.y; bf[2]=(_Float16)v0.z; bf[3]=(_Float16)v0.w;
      bf[4]=(_Float16)v1.x; bf[5]=(_Float16)v1.y; bf[6]=(_Float16)v1.z; bf[7]=(_Float16)v1.w;
      acc2 = __builtin_amdgcn_mfma_f32_16x16x32_f16(a2[ks], bf, acc2, 0, 0, 0);
    }
    float b2v = b2[n];
#pragma unroll
    for (int rr = 0; rr < 4; ++rr){                    // C: row=(q*4+rr), col=c
      int row = w * 16 + q * 4 + rr;
      int uu = (n >> 3) ^ (row & 7);
      h2s[row * 64 + uu * 8 + (n & 7)] = (_Float16)gelu_fast(acc2[rr] + b2v);
    }
  }
  __syncthreads();

  // ---- phase D: MLP3 via f16 MFMA  scales = softplus(h2 @ w3^T) ----
  // N=8 (cols 8..15 computed on clamped w3 row, discarded). 2 MFMA/wave.
  {
    f16x8 a3[2];
#pragma unroll
    for (int ks = 0; ks < 2; ++ks){
      int u = (ks * 4 + q) ^ (am & 7);
      a3[ks] = *(const f16x8*)&h2s[am * 64 + u * 8];
    }
    int n3 = c & 7;
    f32x4 acc3 = {};
#pragma unroll
    for (int ks = 0; ks < 2; ++ks){
      const float4* wp = (const float4*)(w3 + n3 * 64 + ks * 32 + q * 8);
      float4 v0 = wp[0], v1 = wp[1];
      f16x8 bf;
      bf[0]=(_Float16)v0.x; bf[1]=(_Float16)v0.y; bf[2]=(_Float16)v0.z; bf[3]=(_Float16)v0.w;
      bf[4]=(_Float16)v1.x; bf[5]=(_Float16)v1.y; bf[6]=(_Float16)v1.z; bf[7]=(_Float16)v1.w;
      acc3 = __builtin_amdgcn_mfma_f32_16x16x32_f16(a3[ks], bf, acc3, 0, 0, 0);
    }
    if (c < 8){
#pragma unroll
      for (int rr = 0; rr < 4; ++rr){
        int row = w * 16 + q * 4 + rr;
        scalesS[row][c] = softplus_fast(acc3[rr]);
      }
    }
  }
  if (t < 8) gatesS[t] = __builtin_amdgcn_rcpf(1.0f + __expf(-gate_bias[t]));
  __syncthreads();

  // ---- phase E: mixing GEMM, A-fragments straight from global z (L2-hot) ----
  f32x4 acc[8] = {};                    // 8 n-tiles x 4 fp32
  const uint4* wtf = (const uint4*)wt;
  const float* zp = z + base;
#pragma unroll
  for (int ks = 0; ks < 4; ++ks){
    int ak = ks * 32 + q * 8;           // A k-base (contiguous 8)
    const float4* ap = (const float4*)(zp + am * 128 + ak);
    float4 a0 = ap[0], a1 = ap[1];
    ushort8 au;
    au[0]=f2bf(a0.x); au[1]=f2bf(a0.y); au[2]=f2bf(a0.z); au[3]=f2bf(a0.w);
    au[4]=f2bf(a1.x); au[5]=f2bf(a1.y); au[6]=f2bf(a1.z); au[7]=f2bf(a1.w);
    bf16x8 af = __builtin_bit_cast(bf16x8, au);
#pragma unroll
    for (int n = 0; n < 8; ++n){
      uint4 bv = wtf[(n * 4 + ks) * 64 + L];           // L1-hit, coalesced
      bf16x8 bfr = __builtin_bit_cast(bf16x8, bv);
      acc[n] = __builtin_amdgcn_mfma_f32_16x16x32_bf16(af, bfr, acc[n], 0, 0, 0);
    }
  }

  // ---- phase F: epilogue from MFMA C-layout; z re-read from global (L2) ----
  float* op = out + base;
#pragma unroll
  for (int n = 0; n < 8; ++n){          // n == bundle index of output col
    float gate = gatesS[n];
#pragma unroll
    for (int rr = 0; rr < 4; ++rr){
      int row = w * 16 + q * 4 + rr;    // C row = (lane>>4)*4 + reg
      int col = n * 16 + c;             // C col = lane&15
      float zv = zp[row * 128 + col];
      float sc = scalesS[row][n];
      op[row * 128 + col] = __builtin_fmaf(zv, sc, __builtin_fmaf(gate, acc[n][rr], zv));
    }
  }
}

extern "C" void kernel_launch(void* const* d_in, const int* in_sizes, int n_in,
                              void* d_out, int out_size, void* d_ws, size_t ws_size,
                              hipStream_t stream){
  const float* z         = (const float*)d_in[0];
  const float* w1        = (const float*)d_in[1];
  const float* b1        = (const float*)d_in[2];
  const float* w2        = (const float*)d_in[3];
  const float* b2        = (const float*)d_in[4];
  const float* w3        = (const float*)d_in[5];
  const float* mix_w     = (const float*)d_in[6];
  const float* gate_bias = (const float*)d_in[7];
  float* out = (float*)d_out;
  unsigned short* wt = (unsigned short*)d_ws;   // 32 KiB B-fragment cache

  int B = in_sizes[0] / 128;                    // rows
  prepack_wt<<<8, 256, 0, stream>>>(mix_w, wt);
  soft_eq_kernel<<<B / 64, 256, 0, stream>>>(z, w1, b1, w2, b2, w3, gate_bias, wt, out);
}

// Round 2
// 501.520 us; speedup vs baseline: 1.2146x; 1.1480x over previous
//
#include <hip/hip_runtime.h>
#include <hip/hip_fp16.h>

// ---------- types ----------
typedef __bf16   bf16x8 __attribute__((ext_vector_type(8)));
typedef _Float16 f16x8  __attribute__((ext_vector_type(8)));
typedef float    f32x4  __attribute__((ext_vector_type(4)));
typedef unsigned short ushort8 __attribute__((ext_vector_type(8)));

// float -> bf16 RNE (finite inputs)
__device__ __forceinline__ unsigned short f2bf(float f){
  unsigned u = __builtin_bit_cast(unsigned, f);
  u = (u + 0x7FFFu + ((u >> 16) & 1u)) >> 16;
  return (unsigned short)u;
}

// tanh-form GELU with HW exp + HW rcp. Overflow-safe: e=inf -> rcp=0 -> t=1.
__device__ __forceinline__ float gelu_fast(float x){
  float u = 0.7978845608f * x * __builtin_fmaf(0.044715f, x * x, 1.0f);
  float e = __expf(2.0f * __builtin_fabsf(u));
  float t = __builtin_fmaf(-2.0f, __builtin_amdgcn_rcpf(e + 1.0f), 1.0f); // tanh(|u|)
  t = __builtin_copysignf(t, u);
  return 0.5f * x * (1.0f + t);
}

// stable softplus with HW exp/log
__device__ __forceinline__ float softplus_fast(float x){
  float e = __expf(-__builtin_fabsf(x));
  return fmaxf(x, 0.0f) + __logf(1.0f + e);
}

// ---------- workspace layout (ushort units) ----------
//   [0,     16384)  wt   : mix_w bf16 B-fragments (32 KiB)
//   [16384, 20480)  w2p  : w2 f16 B-fragments     (8 KiB)
//   [20480, 21504)  w3p  : w3 f16 B-fragments     (2 KiB)

// ---------- kernel 0: pack mix_w into MFMA B-fragment order (bf16) ----------
// Wt[K=j*16+d][N=i*16+k] = mix_w[i][j][k][d];  frag f = ntile*4 + kstep,
// lane L holds B[k = kstep*32 + (L>>4)*8 + j][n = ntile*16 + (L&15)], j=0..7.
__global__ void prepack_wt(const float* __restrict__ mix_w,
                           unsigned short* __restrict__ wt){
  int tid = blockIdx.x * 256 + threadIdx.x;      // 0..2047
  int f = tid >> 6, L = tid & 63;
  int ks = f & 3, nt = f >> 2;
  int q = L >> 4, c = L & 15;
  int N = nt * 16 + c;
  int i = N >> 4, ko = N & 15;
  unsigned pk[4];
#pragma unroll
  for (int p = 0; p < 4; ++p){
    int K0 = ks * 32 + q * 8 + 2 * p;
    int K1 = K0 + 1;
    unsigned lo = f2bf(mix_w[((i*8 + (K0>>4))*16 + ko)*16 + (K0&15)]);
    unsigned hi = f2bf(mix_w[((i*8 + (K1>>4))*16 + ko)*16 + (K1&15)]);
    pk[p] = lo | (hi << 16);
  }
  uint4 v; v.x = pk[0]; v.y = pk[1]; v.z = pk[2]; v.w = pk[3];
  ((uint4*)wt)[tid] = v;
}

// ---------- kernel 0b: pack w2 / w3 rows into f16 MFMA B-fragments ----------
// w2 frag (nt,ks): lane L, j -> w2[nt*16+(L&15)][ks*32+(L>>4)*8+j]
// w3 frag (ks):    lane L, j -> w3[(L&7)      ][ks*32+(L>>4)*8+j] (cols 8..15 dup)
__global__ void prepack_mlp(const float* __restrict__ w2,
                            const float* __restrict__ w3,
                            unsigned short* __restrict__ ws){
  int tid = blockIdx.x * 256 + threadIdx.x;
  if (tid < 512){
    int f = tid >> 6, L = tid & 63;
    int nt = f >> 1, ks = f & 1, q = L >> 4, c = L & 15;
    const float* s = w2 + (nt*16 + c)*64 + ks*32 + q*8;
    f16x8 h;
#pragma unroll
    for (int j = 0; j < 8; ++j) h[j] = (_Float16)s[j];
    ((f16x8*)(ws + 16384))[tid] = h;
  } else if (tid < 640){
    int u = tid - 512;
    int ks = u >> 6, L = u & 63, q = L >> 4, c = L & 15;
    const float* s = w3 + (c & 7)*64 + ks*32 + q*8;
    f16x8 h;
#pragma unroll
    for (int j = 0; j < 8; ++j) h[j] = (_Float16)s[j];
    ((f16x8*)(ws + 20480))[u] = h;
  }
}

// ---------- main fused kernel: 64 rows/block, 256 threads (4 waves) ----------
// LDS 20512 B total:
//   smemU[0,17408)  : h1s[0,8192) + h2s[8192,16384) (f16, XOR-swizzled);
//                     overlaid in phase F by stage[64][68] f32 (17408 B)
//   nsS  [17408, 20512): norms[64][12] f32 (phase A->B), overlaid by
//                     scales[64][12] (D->F); gates at float idx 768..775
// z path: loaded ONCE in A-fragment register layout (lane owns row w*16+c,
// cols ks*32+q*8..+8). Norms via shfl_xor(16); mixing MFMA runs from these
// registers BEFORE the first barrier (overlaps the whole MLP chain).
// Epilogue re-reads z coalesced from global (L2/L3-hot).
__global__ __launch_bounds__(256, 4)
void soft_eq_kernel(const float* __restrict__ z,
                    const float* __restrict__ w1,  const float* __restrict__ b1,
                    const float* __restrict__ w2,  const float* __restrict__ b2,
                    const float* __restrict__ w3,  const float* __restrict__ gate_bias,
                    const unsigned short* __restrict__ wt,
                    float* __restrict__ out){
  __shared__ __align__(16) unsigned char smemU[17408 + 3104];
  _Float16* h1s = (_Float16*)smemU;                 // [64*64]
  _Float16* h2s = (_Float16*)(smemU + 8192);        // [64*64]
  float*    stageF = (float*)smemU;                 // [64*68] (phase F only)
  float*    nsS = (float*)(smemU + 17408);          // [776] floats

  const int t = threadIdx.x;
  const int w = t >> 6, L = t & 63, q = L >> 4, c = L & 15;
  const size_t base = (size_t)blockIdx.x * (64 * 128);
  const float* zp = z + base;

  // ---- phase A: z -> registers in A-fragment layout + per-bundle norms ----
  const int zrow = w * 16 + c;
  const float* zr0 = zp + zrow * 128;
  float4 zr[8];
#pragma unroll
  for (int ks = 0; ks < 4; ++ks){
    zr[2*ks]   = *(const float4*)(zr0 + ks*32 + q*8);
    zr[2*ks+1] = *(const float4*)(zr0 + ks*32 + q*8 + 4);
  }
#pragma unroll
  for (int ks = 0; ks < 4; ++ks){
    float4 a = zr[2*ks], b = zr[2*ks+1];
    float ss = a.x*a.x + a.y*a.y + a.z*a.z + a.w*a.w
             + b.x*b.x + b.y*b.y + b.z*b.z + b.w*b.w;
    ss += __shfl_xor(ss, 16);                      // pair q <-> q^1
    if (!(L & 16))                                 // q in {0,2}
      nsS[zrow * 12 + 2*ks + (q >> 1)] = sqrtf(ss) + 1e-8f;
  }

  // register-cache per-neuron w1 row + b1 (L1-resident)
  const int i = t & 63;
  float w1r[8];
  { const float4* p = (const float4*)(w1 + i * 8);
    float4 a = p[0], bq = p[1];
    w1r[0]=a.x; w1r[1]=a.y; w1r[2]=a.z; w1r[3]=a.w;
    w1r[4]=bq.x; w1r[5]=bq.y; w1r[6]=bq.z; w1r[7]=bq.w; }
  const float b1r = b1[i];

  // ---- phase E (early): mixing GEMM straight from registers ----
  f32x4 acc[8] = {};                    // 8 n-tiles x 4 fp32
  const uint4* wtf = (const uint4*)wt;
#pragma unroll
  for (int ks = 0; ks < 4; ++ks){
    float4 a0 = zr[2*ks], a1 = zr[2*ks+1];
    ushort8 au;
    au[0]=f2bf(a0.x); au[1]=f2bf(a0.y); au[2]=f2bf(a0.z); au[3]=f2bf(a0.w);
    au[4]=f2bf(a1.x); au[5]=f2bf(a1.y); au[6]=f2bf(a1.z); au[7]=f2bf(a1.w);
    bf16x8 af = __builtin_bit_cast(bf16x8, au);
#pragma unroll
    for (int n = 0; n < 8; ++n){
      uint4 bv = wtf[(n * 4 + ks) * 64 + L];       // L1-hit, coalesced
      bf16x8 bfr = __builtin_bit_cast(bf16x8, bv);
      acc[n] = __builtin_amdgcn_mfma_f32_16x16x32_bf16(af, bfr, acc[n], 0, 0, 0);
    }
  }
  // zr dead here

  __syncthreads();                                 // norms visible

  // ---- phase B: MLP1  h1 = gelu(norms @ w1^T + b1) ----
#pragma unroll
  for (int chunk = 0; chunk < 16; ++chunk){
    int r = chunk * 4 + w;
    const float4* np = (const float4*)&nsS[r * 12];    // wave-broadcast reads
    float4 n0 = np[0], n1 = np[1];
    float pre = b1r + n0.x*w1r[0] + n0.y*w1r[1] + n0.z*w1r[2] + n0.w*w1r[3]
                    + n1.x*w1r[4] + n1.y*w1r[5] + n1.z*w1r[6] + n1.w*w1r[7];
    int u = (i >> 3) ^ (r & 7);                        // swizzled 16B unit
    h1s[r * 64 + u * 8 + (i & 7)] = (_Float16)gelu_fast(pre);
  }
  __syncthreads();

  const int am = w * 16 + c;            // A row for this lane (m = lane&15)

  // ---- phase C: MLP2 via f16 MFMA, prepacked B-fragments ----
  const f16x8* w2f = (const f16x8*)(wt + 16384);
  f16x8 a2[2];
#pragma unroll
  for (int ks = 0; ks < 2; ++ks){
    int u = (ks * 4 + q) ^ (am & 7);
    a2[ks] = *(const f16x8*)&h1s[am * 64 + u * 8];     // conflict-free b128
  }
#pragma unroll
  for (int nt = 0; nt < 4; ++nt){
    int n = nt * 16 + c;
    f32x4 acc2 = {};
#pragma unroll
    for (int ks = 0; ks < 2; ++ks)
      acc2 = __builtin_amdgcn_mfma_f32_16x16x32_f16(a2[ks], w2f[(nt*2+ks)*64 + L],
                                                    acc2, 0, 0, 0);
    float b2v = b2[n];
#pragma unroll
    for (int rr = 0; rr < 4; ++rr){                    // C: row=(q*4+rr), col=c
      int row = w * 16 + q * 4 + rr;
      int uu = (n >> 3) ^ (row & 7);
      h2s[row * 64 + uu * 8 + (n & 7)] = (_Float16)gelu_fast(acc2[rr] + b2v);
    }
  }
  __syncthreads();

  // ---- phase D: MLP3 via f16 MFMA  scales = softplus(h2 @ w3^T) ----
  {
    const f16x8* w3f = (const f16x8*)(wt + 20480);
    f16x8 a3[2];
#pragma unroll
    for (int ks = 0; ks < 2; ++ks){
      int u = (ks * 4 + q) ^ (am & 7);
      a3[ks] = *(const f16x8*)&h2s[am * 64 + u * 8];
    }
    f32x4 acc3 = {};
#pragma unroll
    for (int ks = 0; ks < 2; ++ks)
      acc3 = __builtin_amdgcn_mfma_f32_16x16x32_f16(a3[ks], w3f[ks*64 + L],
                                                    acc3, 0, 0, 0);
    if (c < 8){
#pragma unroll
      for (int rr = 0; rr < 4; ++rr){
        int row = w * 16 + q * 4 + rr;
        nsS[row * 12 + c] = softplus_fast(acc3[rr]);   // scales overlay norms
      }
    }
  }
  if (t < 8) nsS[768 + t] = __builtin_amdgcn_rcpf(1.0f + __expf(-gate_bias[t]));
  __syncthreads();

  // ---- phase F: epilogue, two 64-col halves through LDS stage ----
  float* op = out + base;
#pragma unroll
  for (int half = 0; half < 2; ++half){
#pragma unroll
    for (int np = 0; np < 4; ++np){
      int n = half * 4 + np;
      float g = nsS[768 + n];
#pragma unroll
      for (int rr = 0; rr < 4; ++rr)
        stageF[(w*16 + q*4 + rr) * 68 + np*16 + c] = g * acc[n][rr];
    }
    __syncthreads();
    {
      int row = t >> 2, cc = (t & 3) * 16;
      float sc = nsS[row * 12 + half * 4 + (t & 3)];
      const float4* zr4 = (const float4*)(zp + row * 128 + half * 64 + cc);
      const float*  sp  = &stageF[row * 68 + cc];
      float4*       or4 = (float4*)(op + row * 128 + half * 64 + cc);
#pragma unroll
      for (int k = 0; k < 4; ++k){
        float4 zv = zr4[k];
        float4 st = *(const float4*)(sp + k * 4);
        float4 o;
        o.x = __builtin_fmaf(zv.x, sc, zv.x + st.x);
        o.y = __builtin_fmaf(zv.y, sc, zv.y + st.y);
        o.z = __builtin_fmaf(zv.z, sc, zv.z + st.z);
        o.w = __builtin_fmaf(zv.w, sc, zv.w + st.w);
        or4[k] = o;
      }
    }
    if (half == 0) __syncthreads();     // protect stage before half-1 writes
  }
}

extern "C" void kernel_launch(void* const* d_in, const int* in_sizes, int n_in,
                              void* d_out, int out_size, void* d_ws, size_t ws_size,
                              hipStream_t stream){
  const float* z         = (const float*)d_in[0];
  const float* w1        = (const float*)d_in[1];
  const float* b1        = (const float*)d_in[2];
  const float* w2        = (const float*)d_in[3];
  const float* b2        = (const float*)d_in[4];
  const float* w3        = (const float*)d_in[5];
  const float* mix_w     = (const float*)d_in[6];
  const float* gate_bias = (const float*)d_in[7];
  float* out = (float*)d_out;
  unsigned short* wt = (unsigned short*)d_ws;   // 42 KiB fragment cache

  int B = in_sizes[0] / 128;                    // rows
  prepack_wt<<<8, 256, 0, stream>>>(mix_w, wt);
  prepack_mlp<<<3, 256, 0, stream>>>(w2, w3, wt);
  soft_eq_kernel<<<B / 64, 256, 0, stream>>>(z, w1, b1, w2, b2, w3, gate_bias, wt, out);
}